// Round 1
// baseline (873.262 us; speedup 1.0000x reference)
//
#include <hip/hip_runtime.h>
#include <stdint.h>

typedef __bf16 bf16;
typedef __bf16 bf16x8 __attribute__((ext_vector_type(8)));
typedef __bf16 bf16x4v __attribute__((ext_vector_type(4)));
typedef float f32x4 __attribute__((ext_vector_type(4)));

#define L_SEQ 2048
#define H_DIM 2048
#define KV_DIM 512
#define QKV_LD 3072
#define INTER_DIM 8192

__device__ __forceinline__ void load_lds16(const void* g, void* l) {
  __builtin_amdgcn_global_load_lds(
      (const __attribute__((address_space(1))) void*)g,
      (__attribute__((address_space(3))) void*)l, 16, 0, 0);
}

// ---------------- RMSNorm: fp32 in -> bf16 out ----------------
__global__ __launch_bounds__(256)
void rmsnorm_bf16(const float* __restrict__ x, const float* __restrict__ w,
                  bf16* __restrict__ out) {
  const int row = blockIdx.x;
  const int t = threadIdx.x;
  const float* xr = x + (size_t)row * H_DIM + t * 8;
  float4 a = *(const float4*)xr;
  float4 b = *(const float4*)(xr + 4);
  float ss = a.x * a.x + a.y * a.y + a.z * a.z + a.w * a.w +
             b.x * b.x + b.y * b.y + b.z * b.z + b.w * b.w;
#pragma unroll
  for (int off = 1; off < 64; off <<= 1) ss += __shfl_xor(ss, off, 64);
  __shared__ float red[4];
  if ((t & 63) == 0) red[t >> 6] = ss;
  __syncthreads();
  ss = red[0] + red[1] + red[2] + red[3];
  const float rs = rsqrtf(ss * (1.0f / H_DIM) + 1e-6f);
  float4 w1 = *(const float4*)(w + t * 8);
  float4 w2 = *(const float4*)(w + t * 8 + 4);
  bf16x8 o;
  o[0] = (bf16)(a.x * rs * w1.x);
  o[1] = (bf16)(a.y * rs * w1.y);
  o[2] = (bf16)(a.z * rs * w1.z);
  o[3] = (bf16)(a.w * rs * w1.w);
  o[4] = (bf16)(b.x * rs * w2.x);
  o[5] = (bf16)(b.y * rs * w2.y);
  o[6] = (bf16)(b.z * rs * w2.z);
  o[7] = (bf16)(b.w * rs * w2.w);
  *(bf16x8*)(out + (size_t)row * H_DIM + t * 8) = o;
}

// ---------------- GEMM: C[M,N] = A[M,K](bf16) @ B[N,K](fp32)^T ----------------
// 128x128 tile, BK=32, 4 waves each computing a 64x64 subtile (4x4 MFMAs of
// 16x16x32). A staged via global_load_lds(16B); B fp32 loaded to VGPRs,
// converted to bf16, ds_write. Epilogue fused per MODE.
enum { M_BF16 = 0, M_SILU = 1, M_RES = 2, M_QKV = 3 };

template <int MODE>
__global__ __launch_bounds__(256, 2)
void gemm_bt(const bf16* __restrict__ A, int lda,
             const float* __restrict__ B, int ldb, int K,
             bf16* __restrict__ outb, int ldob,
             float* __restrict__ outf, int ldof,
             const float* __restrict__ res,
             const bf16* __restrict__ gate,
             const float* __restrict__ Bk,
             const float* __restrict__ Bv,
             float* __restrict__ outv) {
  __shared__ bf16 sA[128 * 32];
  __shared__ bf16 sB[128 * 32];
  const int t = threadIdx.x;
  const int lane = t & 63;
  const int l15 = lane & 15, l4 = lane >> 4;
  const int wm = ((t >> 6) >> 1) * 64;
  const int wn = ((t >> 6) & 1) * 64;
  const int m0 = blockIdx.y * 128;
  const int n0 = blockIdx.x * 128;

  const float* Bp = B;
  int bn = n0;
  if (MODE == M_QKV) {
    if (n0 >= 2560)      { Bp = Bv; bn = n0 - 2560; }
    else if (n0 >= 2048) { Bp = Bk; bn = n0 - 2048; }
  }

  const f32x4 zero = {0.f, 0.f, 0.f, 0.f};
  f32x4 acc[4][4];
#pragma unroll
  for (int i = 0; i < 4; ++i)
#pragma unroll
    for (int j = 0; j < 4; ++j) acc[i][j] = zero;

  for (int k0 = 0; k0 < K; k0 += 32) {
    // A tile (128x32 bf16, 8KB): async direct-to-LDS, 2 x 16B per thread
#pragma unroll
    for (int i = 0; i < 2; ++i) {
      const int flat = i * 4096 + t * 16;
      const bf16* asrc =
          A + (size_t)(m0 + (flat >> 6)) * lda + k0 + ((flat & 63) >> 1);
      load_lds16(asrc, (char*)sA + flat);
    }
    // B tile (128x32 fp32 -> bf16): 4 x float4 per thread
    float4 bvv[4];
#pragma unroll
    for (int j = 0; j < 4; ++j) {
      const int fb = j * 4096 + t * 16;
      bvv[j] = *(const float4*)(Bp + (size_t)(bn + (fb >> 7)) * ldb + k0 +
                                ((fb & 127) >> 2));
    }
#pragma unroll
    for (int j = 0; j < 4; ++j) {
      const int fb = j * 4096 + t * 16;
      bf16x4v pk = {(bf16)bvv[j].x, (bf16)bvv[j].y, (bf16)bvv[j].z,
                    (bf16)bvv[j].w};
      *(bf16x4v*)(&sB[(fb >> 7) * 32 + ((fb & 127) >> 2)]) = pk;
    }
    __syncthreads();

    bf16x8 af[4], bfr[4];
#pragma unroll
    for (int mi = 0; mi < 4; ++mi)
      af[mi] = *(const bf16x8*)(&sA[(wm + mi * 16 + l15) * 32 + l4 * 8]);
#pragma unroll
    for (int ni = 0; ni < 4; ++ni)
      bfr[ni] = *(const bf16x8*)(&sB[(wn + ni * 16 + l15) * 32 + l4 * 8]);
#pragma unroll
    for (int mi = 0; mi < 4; ++mi)
#pragma unroll
      for (int ni = 0; ni < 4; ++ni)
        acc[mi][ni] = __builtin_amdgcn_mfma_f32_16x16x32_bf16(
            af[mi], bfr[ni], acc[mi][ni], 0, 0, 0);
    __syncthreads();
  }

  // Epilogue. C/D layout: col = lane&15, row = (lane>>4)*4 + reg (m89/m91).
#pragma unroll
  for (int mi = 0; mi < 4; ++mi) {
#pragma unroll
    for (int ni = 0; ni < 4; ++ni) {
      const int row0 = m0 + wm + mi * 16 + l4 * 4;
      const int col = n0 + wn + ni * 16 + l15;
#pragma unroll
      for (int r = 0; r < 4; ++r) {
        const float c = acc[mi][ni][r];
        const size_t m = (size_t)(row0 + r);
        if (MODE == M_BF16) {
          outb[m * ldob + col] = (bf16)c;
        } else if (MODE == M_SILU) {
          const float g = (float)gate[m * ldob + col];
          const float s = g / (1.f + __expf(-g));
          outb[m * ldob + col] = (bf16)(s * c);
        } else if (MODE == M_RES) {
          outf[m * ldof + col] = c + res[m * ldof + col];
        } else {  // M_QKV: bf16 to qkv buffer; K/V cols also fp32 to d_out
          outb[m * QKV_LD + col] = (bf16)c;
          if (col >= 2560)      outv[m * KV_DIM + (col - 2560)] = c;
          else if (col >= 2048) outf[m * KV_DIM + (col - 2048)] = c;
        }
      }
    }
  }
}

// ---------------- Flash attention, segment-causal ----------------
// grid = (32 q-tiles of 64 rows, 16 heads), 256 threads (4 waves, 16 Q rows
// each). Segment boundaries (512/1280) are 64-multiples, so each q-tile lies
// in one segment. Q pre-scaled by 1/sqrt(128).
__global__ __launch_bounds__(256, 2)
void attn_fwd(const bf16* __restrict__ qkv, const int* __restrict__ cu,
              bf16* __restrict__ out) {
  const int h = blockIdx.y;
  const int q0 = blockIdx.x * 64;
  const int kvh = h >> 2;  // repeat_interleave: kv head = h / 4
  const int t = threadIdx.x;
  const int lane = t & 63;
  const int w = t >> 6;
  const int l15 = lane & 15, l4 = lane >> 4;

  __shared__ bf16 sK[64 * 136];  // padded rows (272B) to spread banks
  __shared__ bf16 sV[64 * 136];
  __shared__ bf16 sP[4][16 * 64];

  const int c1 = cu[1], c2 = cu[2];
  const int seg0 = (q0 >= c2) ? c2 : ((q0 >= c1) ? c1 : 0);

  const int qrow = q0 + w * 16 + l15;
  bf16x8 qf[4];
#pragma unroll
  for (int kc = 0; kc < 4; ++kc) {
    bf16x8 v = *(const bf16x8*)(qkv + (size_t)qrow * QKV_LD + h * 128 +
                                kc * 32 + l4 * 8);
#pragma unroll
    for (int j = 0; j < 8; ++j)
      v[j] = (bf16)((float)v[j] * 0.08838834764831845f);
    qf[kc] = v;
  }

  const f32x4 zero = {0.f, 0.f, 0.f, 0.f};
  f32x4 oacc[8];
#pragma unroll
  for (int i = 0; i < 8; ++i) oacc[i] = zero;
  float mi[4] = {-1e30f, -1e30f, -1e30f, -1e30f};
  float li[4] = {0.f, 0.f, 0.f, 0.f};

  for (int k0 = seg0; k0 <= q0; k0 += 64) {
    // stage K,V tiles (64 x 128 bf16 each)
#pragma unroll
    for (int it = 0; it < 4; ++it) {
      const int flat = it * 4096 + t * 16;
      const int r = flat >> 8, db = flat & 255;
      const char* krow =
          (const char*)(qkv + (size_t)(k0 + r) * QKV_LD + 2048 + kvh * 128);
      const char* vrow =
          (const char*)(qkv + (size_t)(k0 + r) * QKV_LD + 2560 + kvh * 128);
      *(bf16x8*)((char*)sK + r * 272 + db) = *(const bf16x8*)(krow + db);
      *(bf16x8*)((char*)sV + r * 272 + db) = *(const bf16x8*)(vrow + db);
    }
    __syncthreads();

    // S = Q K^T : 16 q-rows x 64 keys per wave
    f32x4 sacc[4];
#pragma unroll
    for (int kg = 0; kg < 4; ++kg) {
      f32x4 a = zero;
#pragma unroll
      for (int kc = 0; kc < 4; ++kc) {
        bf16x8 kf = *(const bf16x8*)((const char*)sK +
                                     (kg * 16 + l15) * 272 + kc * 64 + l4 * 16);
        a = __builtin_amdgcn_mfma_f32_16x16x32_bf16(qf[kc], kf, a, 0, 0, 0);
      }
      sacc[kg] = a;
    }

    if (k0 == q0) {  // causal mask (diagonal tile only)
#pragma unroll
      for (int kg = 0; kg < 4; ++kg) {
        const int kk = kg * 16 + l15;
#pragma unroll
        for (int r = 0; r < 4; ++r) {
          const int qq = w * 16 + l4 * 4 + r;
          if (kk > qq) sacc[kg][r] = -1e30f;
        }
      }
    }

    // online softmax; row r state replicated across the 16-lane col group
    float mx[4], al[4], rs[4];
#pragma unroll
    for (int r = 0; r < 4; ++r)
      mx[r] = fmaxf(fmaxf(sacc[0][r], sacc[1][r]),
                    fmaxf(sacc[2][r], sacc[3][r]));
#pragma unroll
    for (int off = 1; off < 16; off <<= 1)
#pragma unroll
      for (int r = 0; r < 4; ++r)
        mx[r] = fmaxf(mx[r], __shfl_xor(mx[r], off, 64));
#pragma unroll
    for (int r = 0; r < 4; ++r) {
      const float mn = fmaxf(mi[r], mx[r]);
      al[r] = __expf(mi[r] - mn);
      mi[r] = mn;
      rs[r] = 0.f;
    }
#pragma unroll
    for (int kg = 0; kg < 4; ++kg)
#pragma unroll
      for (int r = 0; r < 4; ++r) {
        const float p = __expf(sacc[kg][r] - mi[r]);
        sacc[kg][r] = p;
        rs[r] += p;
      }
#pragma unroll
    for (int off = 1; off < 16; off <<= 1)
#pragma unroll
      for (int r = 0; r < 4; ++r) rs[r] += __shfl_xor(rs[r], off, 64);
#pragma unroll
    for (int r = 0; r < 4; ++r) li[r] = li[r] * al[r] + rs[r];
#pragma unroll
    for (int dn = 0; dn < 8; ++dn)
#pragma unroll
      for (int r = 0; r < 4; ++r) oacc[dn][r] *= al[r];

    // P: C-layout -> LDS -> A-layout (per-wave private region)
#pragma unroll
    for (int kg = 0; kg < 4; ++kg)
#pragma unroll
      for (int r = 0; r < 4; ++r)
        sP[w][(l4 * 4 + r) * 64 + kg * 16 + l15] = (bf16)sacc[kg][r];
    __syncthreads();

    bf16x8 pf[2];
#pragma unroll
    for (int kc2 = 0; kc2 < 2; ++kc2)
      pf[kc2] = *(const bf16x8*)(&sP[w][l15 * 64 + kc2 * 32 + l4 * 8]);
#pragma unroll
    for (int dn = 0; dn < 8; ++dn)
#pragma unroll
      for (int kc2 = 0; kc2 < 2; ++kc2) {
        bf16x8 vf;
#pragma unroll
        for (int j = 0; j < 8; ++j)
          vf[j] = sV[(kc2 * 32 + l4 * 8 + j) * 136 + dn * 16 + l15];
        oacc[dn] =
            __builtin_amdgcn_mfma_f32_16x16x32_bf16(pf[kc2], vf, oacc[dn], 0, 0, 0);
      }
    __syncthreads();
  }

#pragma unroll
  for (int dn = 0; dn < 8; ++dn)
#pragma unroll
    for (int r = 0; r < 4; ++r) {
      const size_t m = (size_t)(q0 + w * 16 + l4 * 4 + r);
      out[m * H_DIM + h * 128 + dn * 16 + l15] = (bf16)(oacc[dn][r] / li[r]);
    }
}

// ---------------- Host launcher ----------------
extern "C" void kernel_launch(void* const* d_in, const int* in_sizes, int n_in,
                              void* d_out, int out_size, void* d_ws,
                              size_t ws_size, hipStream_t stream) {
  (void)in_sizes; (void)n_in; (void)out_size; (void)ws_size;
  const float* hs     = (const float*)d_in[0];
  const int*   cu     = (const int*)d_in[1];
  const float* ln1    = (const float*)d_in[2];
  const float* ln2    = (const float*)d_in[3];
  const float* q_w    = (const float*)d_in[4];
  const float* k_w    = (const float*)d_in[5];
  const float* v_w    = (const float*)d_in[6];
  const float* o_w    = (const float*)d_in[7];
  const float* gate_w = (const float*)d_in[8];
  const float* up_w   = (const float*)d_in[9];
  const float* down_w = (const float*)d_in[10];

  float* out_hidden = (float*)d_out;
  float* out_k = out_hidden + (size_t)L_SEQ * H_DIM;
  float* out_v = out_k + (size_t)L_SEQ * KV_DIM;

  char* ws = (char*)d_ws;
  bf16*  normed1 = (bf16*)(ws);                          //  8 MB
  bf16*  qkv     = (bf16*)(ws + ((size_t)8 << 20));      // 12 MB
  bf16*  attnb   = (bf16*)(ws + ((size_t)20 << 20));     //  8 MB
  float* hidden  = (float*)(ws + ((size_t)28 << 20));    // 16 MB
  bf16*  normed2 = (bf16*)(ws + ((size_t)44 << 20));     //  8 MB
  bf16*  gateb   = (bf16*)(ws + ((size_t)52 << 20));     // 32 MB
  bf16*  interb  = (bf16*)(ws + ((size_t)84 << 20));     // 32 MB (ends 116 MB)

  dim3 blk(256);

  // 1) normed1 = rmsnorm(hidden_states) -> bf16
  rmsnorm_bf16<<<L_SEQ, blk, 0, stream>>>(hs, ln1, normed1);

  // 2) fused QKV projection (N = 2048 + 512 + 512)
  gemm_bt<M_QKV><<<dim3(24, 16), blk, 0, stream>>>(
      normed1, H_DIM, q_w, H_DIM, H_DIM, qkv, QKV_LD, out_k, KV_DIM, nullptr,
      nullptr, k_w, v_w, out_v);

  // 3) attention
  attn_fwd<<<dim3(32, 16), blk, 0, stream>>>(qkv, cu, attnb);

  // 4) O projection + residual -> hidden (fp32)
  gemm_bt<M_RES><<<dim3(16, 16), blk, 0, stream>>>(
      attnb, H_DIM, o_w, H_DIM, H_DIM, nullptr, 0, hidden, H_DIM, hs, nullptr,
      nullptr, nullptr, nullptr);

  // 5) normed2 = rmsnorm(hidden) -> bf16
  rmsnorm_bf16<<<L_SEQ, blk, 0, stream>>>(hidden, ln2, normed2);

  // 6) gate = normed2 @ gate_w^T (bf16)
  gemm_bt<M_BF16><<<dim3(64, 16), blk, 0, stream>>>(
      normed2, H_DIM, gate_w, H_DIM, H_DIM, gateb, INTER_DIM, nullptr, 0,
      nullptr, nullptr, nullptr, nullptr, nullptr);

  // 7) inter = silu(gate) * (normed2 @ up_w^T) (bf16)
  gemm_bt<M_SILU><<<dim3(64, 16), blk, 0, stream>>>(
      normed2, H_DIM, up_w, H_DIM, H_DIM, interb, INTER_DIM, nullptr, 0,
      nullptr, gateb, nullptr, nullptr, nullptr);

  // 8) out = hidden + inter @ down_w^T (fp32 to d_out)
  gemm_bt<M_RES><<<dim3(16, 16), blk, 0, stream>>>(
      interb, INTER_DIM, down_w, INTER_DIM, INTER_DIM, nullptr, 0, out_hidden,
      H_DIM, hidden, nullptr, nullptr, nullptr, nullptr);
}

// Round 2
// 705.062 us; speedup vs baseline: 1.2386x; 1.2386x over previous
//
#include <hip/hip_runtime.h>
#include <stdint.h>

typedef __bf16 bf16;
typedef __bf16 bf16x8 __attribute__((ext_vector_type(8)));
typedef float f32x4 __attribute__((ext_vector_type(4)));

#define L_SEQ 2048
#define H_DIM 2048
#define KV_DIM 512
#define QKV_LD 3072
#define INTER_DIM 8192

__device__ __forceinline__ void load_lds16(const void* g, void* l) {
  __builtin_amdgcn_global_load_lds(
      (const __attribute__((address_space(1))) void*)g,
      (__attribute__((address_space(3))) void*)l, 16, 0, 0);
}

// ---------------- fp32 -> bf16 weight convert ----------------
__global__ __launch_bounds__(256)
void cvt_bf16(const float* __restrict__ s, bf16* __restrict__ d) {
  const size_t i = ((size_t)blockIdx.x * 256 + threadIdx.x) * 8;
  float4 a = *(const float4*)(s + i);
  float4 b = *(const float4*)(s + i + 4);
  bf16x8 o;
  o[0] = (bf16)a.x; o[1] = (bf16)a.y; o[2] = (bf16)a.z; o[3] = (bf16)a.w;
  o[4] = (bf16)b.x; o[5] = (bf16)b.y; o[6] = (bf16)b.z; o[7] = (bf16)b.w;
  *(bf16x8*)(d + i) = o;
}

// ---------------- RMSNorm: fp32 in -> bf16 out ----------------
__global__ __launch_bounds__(256)
void rmsnorm_bf16(const float* __restrict__ x, const float* __restrict__ w,
                  bf16* __restrict__ out) {
  const int row = blockIdx.x;
  const int t = threadIdx.x;
  const float* xr = x + (size_t)row * H_DIM + t * 8;
  float4 a = *(const float4*)xr;
  float4 b = *(const float4*)(xr + 4);
  float ss = a.x * a.x + a.y * a.y + a.z * a.z + a.w * a.w +
             b.x * b.x + b.y * b.y + b.z * b.z + b.w * b.w;
#pragma unroll
  for (int off = 1; off < 64; off <<= 1) ss += __shfl_xor(ss, off, 64);
  __shared__ float red[4];
  if ((t & 63) == 0) red[t >> 6] = ss;
  __syncthreads();
  ss = red[0] + red[1] + red[2] + red[3];
  const float rs = rsqrtf(ss * (1.0f / H_DIM) + 1e-6f);
  float4 w1 = *(const float4*)(w + t * 8);
  float4 w2 = *(const float4*)(w + t * 8 + 4);
  bf16x8 o;
  o[0] = (bf16)(a.x * rs * w1.x);
  o[1] = (bf16)(a.y * rs * w1.y);
  o[2] = (bf16)(a.z * rs * w1.z);
  o[3] = (bf16)(a.w * rs * w1.w);
  o[4] = (bf16)(b.x * rs * w2.x);
  o[5] = (bf16)(b.y * rs * w2.y);
  o[6] = (bf16)(b.z * rs * w2.z);
  o[7] = (bf16)(b.w * rs * w2.w);
  *(bf16x8*)(out + (size_t)row * H_DIM + t * 8) = o;
}

// ---------------- GEMM: C[M,N] = A[M,K](bf16) @ B[N,K](bf16)^T -------------
// 128x128 tile, BK=32. Both A and B staged via global_load_lds(16B).
// MODE: M_PART writes fp32 partials (split-K via blockIdx.z);
//       M_QKV writes bf16 qkv + fp32 K/V slices to d_out.
enum { M_PART = 0, M_QKV = 1 };

template <int MODE>
__global__ __launch_bounds__(256, 2)
void gemm_bt(const bf16* __restrict__ A, int lda,
             const bf16* __restrict__ B, int ldb, int kpb,
             bf16* __restrict__ outb, int ldob,
             float* __restrict__ outf, int ldof, size_t zstride,
             float* __restrict__ outk, float* __restrict__ outv) {
  __shared__ bf16 sA[128 * 32];
  __shared__ bf16 sB[128 * 32];
  const int t = threadIdx.x;
  const int lane = t & 63;
  const int l15 = lane & 15, l4 = lane >> 4;
  const int wm = ((t >> 6) >> 1) * 64;
  const int wn = ((t >> 6) & 1) * 64;
  const int m0 = blockIdx.y * 128;
  const int n0 = blockIdx.x * 128;
  const int kbeg = blockIdx.z * kpb;
  const int kend = kbeg + kpb;

  const f32x4 zero = {0.f, 0.f, 0.f, 0.f};
  f32x4 acc[4][4];
#pragma unroll
  for (int i = 0; i < 4; ++i)
#pragma unroll
    for (int j = 0; j < 4; ++j) acc[i][j] = zero;

  for (int k0 = kbeg; k0 < kend; k0 += 32) {
#pragma unroll
    for (int i = 0; i < 2; ++i) {
      const int flat = i * 4096 + t * 16;
      const int r = flat >> 6, cb = (flat & 63) >> 1;
      load_lds16(A + (size_t)(m0 + r) * lda + k0 + cb, (char*)sA + flat);
      load_lds16(B + (size_t)(n0 + r) * ldb + k0 + cb, (char*)sB + flat);
    }
    __syncthreads();

    bf16x8 af[4], bfr[4];
#pragma unroll
    for (int mi = 0; mi < 4; ++mi)
      af[mi] = *(const bf16x8*)(&sA[(wm + mi * 16 + l15) * 32 + l4 * 8]);
#pragma unroll
    for (int ni = 0; ni < 4; ++ni)
      bfr[ni] = *(const bf16x8*)(&sB[(wn + ni * 16 + l15) * 32 + l4 * 8]);
#pragma unroll
    for (int mi = 0; mi < 4; ++mi)
#pragma unroll
      for (int ni = 0; ni < 4; ++ni)
        acc[mi][ni] = __builtin_amdgcn_mfma_f32_16x16x32_bf16(
            af[mi], bfr[ni], acc[mi][ni], 0, 0, 0);
    __syncthreads();
  }

  // C/D layout: col = lane&15, row = (lane>>4)*4 + reg (m89/m91).
#pragma unroll
  for (int mi = 0; mi < 4; ++mi) {
#pragma unroll
    for (int ni = 0; ni < 4; ++ni) {
      const int row0 = m0 + wm + mi * 16 + l4 * 4;
      const int col = n0 + wn + ni * 16 + l15;
#pragma unroll
      for (int r = 0; r < 4; ++r) {
        const float c = acc[mi][ni][r];
        const size_t m = (size_t)(row0 + r);
        if (MODE == M_PART) {
          outf[zstride * blockIdx.z + m * ldof + col] = c;
        } else {  // M_QKV
          outb[m * QKV_LD + col] = (bf16)c;
          if (col >= 2560)      outv[m * KV_DIM + (col - 2560)] = c;
          else if (col >= 2048) outk[m * KV_DIM + (col - 2048)] = c;
        }
      }
    }
  }
}

// ---------------- Fused gate+up GLU GEMM ----------------
// C_g and C_u share the A tile; epilogue writes silu(g)*u in bf16.
__global__ __launch_bounds__(256, 2)
void gemm_glu(const bf16* __restrict__ A, const bf16* __restrict__ Bg,
              const bf16* __restrict__ Bu, bf16* __restrict__ out) {
  __shared__ bf16 sA[128 * 32];
  __shared__ bf16 sG[128 * 32];
  __shared__ bf16 sU[128 * 32];
  const int t = threadIdx.x;
  const int lane = t & 63;
  const int l15 = lane & 15, l4 = lane >> 4;
  const int wm = ((t >> 6) >> 1) * 64;
  const int wn = ((t >> 6) & 1) * 64;
  const int m0 = blockIdx.y * 128;
  const int n0 = blockIdx.x * 128;

  const f32x4 zero = {0.f, 0.f, 0.f, 0.f};
  f32x4 ag[4][4], au[4][4];
#pragma unroll
  for (int i = 0; i < 4; ++i)
#pragma unroll
    for (int j = 0; j < 4; ++j) { ag[i][j] = zero; au[i][j] = zero; }

  for (int k0 = 0; k0 < H_DIM; k0 += 32) {
#pragma unroll
    for (int i = 0; i < 2; ++i) {
      const int flat = i * 4096 + t * 16;
      const int r = flat >> 6, cb = (flat & 63) >> 1;
      load_lds16(A + (size_t)(m0 + r) * H_DIM + k0 + cb, (char*)sA + flat);
      load_lds16(Bg + (size_t)(n0 + r) * H_DIM + k0 + cb, (char*)sG + flat);
      load_lds16(Bu + (size_t)(n0 + r) * H_DIM + k0 + cb, (char*)sU + flat);
    }
    __syncthreads();

    bf16x8 af[4], bg[4], bu[4];
#pragma unroll
    for (int mi = 0; mi < 4; ++mi)
      af[mi] = *(const bf16x8*)(&sA[(wm + mi * 16 + l15) * 32 + l4 * 8]);
#pragma unroll
    for (int ni = 0; ni < 4; ++ni) {
      bg[ni] = *(const bf16x8*)(&sG[(wn + ni * 16 + l15) * 32 + l4 * 8]);
      bu[ni] = *(const bf16x8*)(&sU[(wn + ni * 16 + l15) * 32 + l4 * 8]);
    }
#pragma unroll
    for (int mi = 0; mi < 4; ++mi)
#pragma unroll
      for (int ni = 0; ni < 4; ++ni) {
        ag[mi][ni] = __builtin_amdgcn_mfma_f32_16x16x32_bf16(
            af[mi], bg[ni], ag[mi][ni], 0, 0, 0);
        au[mi][ni] = __builtin_amdgcn_mfma_f32_16x16x32_bf16(
            af[mi], bu[ni], au[mi][ni], 0, 0, 0);
      }
    __syncthreads();
  }

#pragma unroll
  for (int mi = 0; mi < 4; ++mi) {
#pragma unroll
    for (int ni = 0; ni < 4; ++ni) {
      const int row0 = m0 + wm + mi * 16 + l4 * 4;
      const int col = n0 + wn + ni * 16 + l15;
#pragma unroll
      for (int r = 0; r < 4; ++r) {
        const float g = ag[mi][ni][r];
        const float u = au[mi][ni][r];
        const float s = g / (1.f + __expf(-g));
        out[(size_t)(row0 + r) * INTER_DIM + col] = (bf16)(s * u);
      }
    }
  }
}

// ---------------- reduce: out = p0 + p1 + res (float4) ----------------
__global__ __launch_bounds__(256)
void reduce_add2(const float* __restrict__ p0, const float* __restrict__ p1,
                 const float* __restrict__ res, float* __restrict__ out) {
  const size_t i = ((size_t)blockIdx.x * 256 + threadIdx.x) * 4;
  float4 a = *(const float4*)(p0 + i);
  float4 b = *(const float4*)(p1 + i);
  float4 c = *(const float4*)(res + i);
  float4 o;
  o.x = a.x + b.x + c.x;
  o.y = a.y + b.y + c.y;
  o.z = a.z + b.z + c.z;
  o.w = a.w + b.w + c.w;
  *(float4*)(out + i) = o;
}

// ---------------- Flash attention, segment-causal ----------------
__global__ __launch_bounds__(256, 2)
void attn_fwd(const bf16* __restrict__ qkv, const int* __restrict__ cu,
              bf16* __restrict__ out) {
  const int h = blockIdx.y;
  const int q0 = blockIdx.x * 64;
  const int kvh = h >> 2;
  const int t = threadIdx.x;
  const int lane = t & 63;
  const int w = t >> 6;
  const int l15 = lane & 15, l4 = lane >> 4;

  __shared__ bf16 sK[64 * 136];
  __shared__ bf16 sV[64 * 136];
  __shared__ bf16 sP[4][16 * 64];

  const int c1 = cu[1], c2 = cu[2];
  const int seg0 = (q0 >= c2) ? c2 : ((q0 >= c1) ? c1 : 0);

  const int qrow = q0 + w * 16 + l15;
  bf16x8 qf[4];
#pragma unroll
  for (int kc = 0; kc < 4; ++kc) {
    bf16x8 v = *(const bf16x8*)(qkv + (size_t)qrow * QKV_LD + h * 128 +
                                kc * 32 + l4 * 8);
#pragma unroll
    for (int j = 0; j < 8; ++j)
      v[j] = (bf16)((float)v[j] * 0.08838834764831845f);
    qf[kc] = v;
  }

  const f32x4 zero = {0.f, 0.f, 0.f, 0.f};
  f32x4 oacc[8];
#pragma unroll
  for (int i = 0; i < 8; ++i) oacc[i] = zero;
  float mi[4] = {-1e30f, -1e30f, -1e30f, -1e30f};
  float li[4] = {0.f, 0.f, 0.f, 0.f};

  for (int k0 = seg0; k0 <= q0; k0 += 64) {
#pragma unroll
    for (int it = 0; it < 4; ++it) {
      const int flat = it * 4096 + t * 16;
      const int r = flat >> 8, db = flat & 255;
      const char* krow =
          (const char*)(qkv + (size_t)(k0 + r) * QKV_LD + 2048 + kvh * 128);
      const char* vrow =
          (const char*)(qkv + (size_t)(k0 + r) * QKV_LD + 2560 + kvh * 128);
      *(bf16x8*)((char*)sK + r * 272 + db) = *(const bf16x8*)(krow + db);
      *(bf16x8*)((char*)sV + r * 272 + db) = *(const bf16x8*)(vrow + db);
    }
    __syncthreads();

    f32x4 sacc[4];
#pragma unroll
    for (int kg = 0; kg < 4; ++kg) {
      f32x4 a = zero;
#pragma unroll
      for (int kc = 0; kc < 4; ++kc) {
        bf16x8 kf = *(const bf16x8*)((const char*)sK +
                                     (kg * 16 + l15) * 272 + kc * 64 + l4 * 16);
        a = __builtin_amdgcn_mfma_f32_16x16x32_bf16(qf[kc], kf, a, 0, 0, 0);
      }
      sacc[kg] = a;
    }

    if (k0 == q0) {
#pragma unroll
      for (int kg = 0; kg < 4; ++kg) {
        const int kk = kg * 16 + l15;
#pragma unroll
        for (int r = 0; r < 4; ++r) {
          const int qq = w * 16 + l4 * 4 + r;
          if (kk > qq) sacc[kg][r] = -1e30f;
        }
      }
    }

    float mx[4], al[4], rs[4];
#pragma unroll
    for (int r = 0; r < 4; ++r)
      mx[r] = fmaxf(fmaxf(sacc[0][r], sacc[1][r]),
                    fmaxf(sacc[2][r], sacc[3][r]));
#pragma unroll
    for (int off = 1; off < 16; off <<= 1)
#pragma unroll
      for (int r = 0; r < 4; ++r)
        mx[r] = fmaxf(mx[r], __shfl_xor(mx[r], off, 64));
#pragma unroll
    for (int r = 0; r < 4; ++r) {
      const float mn = fmaxf(mi[r], mx[r]);
      al[r] = __expf(mi[r] - mn);
      mi[r] = mn;
      rs[r] = 0.f;
    }
#pragma unroll
    for (int kg = 0; kg < 4; ++kg)
#pragma unroll
      for (int r = 0; r < 4; ++r) {
        const float p = __expf(sacc[kg][r] - mi[r]);
        sacc[kg][r] = p;
        rs[r] += p;
      }
#pragma unroll
    for (int off = 1; off < 16; off <<= 1)
#pragma unroll
      for (int r = 0; r < 4; ++r) rs[r] += __shfl_xor(rs[r], off, 64);
#pragma unroll
    for (int r = 0; r < 4; ++r) li[r] = li[r] * al[r] + rs[r];
#pragma unroll
    for (int dn = 0; dn < 8; ++dn)
#pragma unroll
      for (int r = 0; r < 4; ++r) oacc[dn][r] *= al[r];

#pragma unroll
    for (int kg = 0; kg < 4; ++kg)
#pragma unroll
      for (int r = 0; r < 4; ++r)
        sP[w][(l4 * 4 + r) * 64 + kg * 16 + l15] = (bf16)sacc[kg][r];
    __syncthreads();

    bf16x8 pf[2];
#pragma unroll
    for (int kc2 = 0; kc2 < 2; ++kc2)
      pf[kc2] = *(const bf16x8*)(&sP[w][l15 * 64 + kc2 * 32 + l4 * 8]);
#pragma unroll
    for (int dn = 0; dn < 8; ++dn)
#pragma unroll
      for (int kc2 = 0; kc2 < 2; ++kc2) {
        bf16x8 vf;
#pragma unroll
        for (int j = 0; j < 8; ++j)
          vf[j] = sV[(kc2 * 32 + l4 * 8 + j) * 136 + dn * 16 + l15];
        oacc[dn] =
            __builtin_amdgcn_mfma_f32_16x16x32_bf16(pf[kc2], vf, oacc[dn], 0, 0, 0);
      }
    __syncthreads();
  }

#pragma unroll
  for (int dn = 0; dn < 8; ++dn)
#pragma unroll
    for (int r = 0; r < 4; ++r) {
      const size_t m = (size_t)(q0 + w * 16 + l4 * 4 + r);
      out[m * H_DIM + h * 128 + dn * 16 + l15] = (bf16)(oacc[dn][r] / li[r]);
    }
}

// ---------------- Host launcher ----------------
extern "C" void kernel_launch(void* const* d_in, const int* in_sizes, int n_in,
                              void* d_out, int out_size, void* d_ws,
                              size_t ws_size, hipStream_t stream) {
  (void)in_sizes; (void)n_in; (void)out_size; (void)ws_size;
  const float* hs     = (const float*)d_in[0];
  const int*   cu     = (const int*)d_in[1];
  const float* ln1    = (const float*)d_in[2];
  const float* ln2    = (const float*)d_in[3];
  const float* q_w    = (const float*)d_in[4];
  const float* k_w    = (const float*)d_in[5];
  const float* v_w    = (const float*)d_in[6];
  const float* o_w    = (const float*)d_in[7];
  const float* gate_w = (const float*)d_in[8];
  const float* up_w   = (const float*)d_in[9];
  const float* down_w = (const float*)d_in[10];

  float* out_hidden = (float*)d_out;                       // also the fp32 "hidden"
  float* out_k = out_hidden + (size_t)L_SEQ * H_DIM;
  float* out_v = out_k + (size_t)L_SEQ * KV_DIM;

  char* ws = (char*)d_ws;
  // converted weights (bf16), stacked: q | k | v | o | gate | up | down
  bf16* WB = (bf16*)ws;                                    // 116 MB
  const size_t wq_off = 0;
  const size_t wk_off = 4194304;
  const size_t wv_off = 5242880;
  const size_t wo_off = 6291456;
  const size_t wg_off = 10485760;
  const size_t wu_off = 27262976;
  const size_t wd_off = 44040192;

  bf16*  normed1 = (bf16*)(ws + ((size_t)116 << 20));      //  8 MB
  bf16*  qkv     = (bf16*)(ws + ((size_t)124 << 20));      // 12 MB
  bf16*  attnb   = (bf16*)(ws + ((size_t)136 << 20));      //  8 MB
  bf16*  normed2 = (bf16*)(ws + ((size_t)144 << 20));      //  8 MB
  bf16*  interb  = (bf16*)(ws + ((size_t)152 << 20));      // 32 MB (ends 184)
  // O-proj partials overlay interb (free until GLU GEMM)
  float* opart   = (float*)(ws + ((size_t)152 << 20));     // 2 x 16 MB
  // down-proj partials overlay normed1..normed2 (free by then)
  float* dpart   = (float*)(ws + ((size_t)116 << 20));     // 2 x 16 MB

  dim3 blk(256);

  // 0) convert all weights to bf16
  cvt_bf16<<<2048, blk, 0, stream>>>(q_w,    WB + wq_off);
  cvt_bf16<<< 512, blk, 0, stream>>>(k_w,    WB + wk_off);
  cvt_bf16<<< 512, blk, 0, stream>>>(v_w,    WB + wv_off);
  cvt_bf16<<<2048, blk, 0, stream>>>(o_w,    WB + wo_off);
  cvt_bf16<<<8192, blk, 0, stream>>>(gate_w, WB + wg_off);
  cvt_bf16<<<8192, blk, 0, stream>>>(up_w,   WB + wu_off);
  cvt_bf16<<<8192, blk, 0, stream>>>(down_w, WB + wd_off);

  // 1) normed1 = rmsnorm(hidden_states)
  rmsnorm_bf16<<<L_SEQ, blk, 0, stream>>>(hs, ln1, normed1);

  // 2) QKV projection (B = stacked q|k|v, N = 3072)
  gemm_bt<M_QKV><<<dim3(24, 16, 1), blk, 0, stream>>>(
      normed1, H_DIM, WB + wq_off, H_DIM, H_DIM, qkv, QKV_LD, nullptr, 0, 0,
      out_k, out_v);

  // 3) attention
  attn_fwd<<<dim3(32, 16), blk, 0, stream>>>(qkv, cu, attnb);

  // 4) O projection, split-K=2 -> partials
  gemm_bt<M_PART><<<dim3(16, 16, 2), blk, 0, stream>>>(
      attnb, H_DIM, WB + wo_off, H_DIM, 1024, nullptr, 0, opart, H_DIM,
      (size_t)L_SEQ * H_DIM, nullptr, nullptr);
  // hidden = opart0 + opart1 + hs  (stored in d_out)
  reduce_add2<<<4096, blk, 0, stream>>>(opart, opart + (size_t)L_SEQ * H_DIM,
                                        hs, out_hidden);

  // 5) normed2 = rmsnorm(hidden)
  rmsnorm_bf16<<<L_SEQ, blk, 0, stream>>>(out_hidden, ln2, normed2);

  // 6) inter = silu(normed2 @ gate^T) * (normed2 @ up^T)  (fused GLU)
  gemm_glu<<<dim3(64, 16), blk, 0, stream>>>(normed2, WB + wg_off, WB + wu_off,
                                             interb);

  // 7) down projection, split-K=2 -> partials
  gemm_bt<M_PART><<<dim3(16, 16, 2), blk, 0, stream>>>(
      interb, INTER_DIM, WB + wd_off, INTER_DIM, 4096, nullptr, 0, dpart,
      H_DIM, (size_t)L_SEQ * H_DIM, nullptr, nullptr);
  // out = dpart0 + dpart1 + hidden (in place on d_out)
  reduce_add2<<<4096, blk, 0, stream>>>(dpart, dpart + (size_t)L_SEQ * H_DIM,
                                        out_hidden, out_hidden);
}

// Round 3
// 664.989 us; speedup vs baseline: 1.3132x; 1.0603x over previous
//
#include <hip/hip_runtime.h>
#include <stdint.h>

typedef __bf16 bf16;
typedef __bf16 bf16x8 __attribute__((ext_vector_type(8)));
typedef float f32x4 __attribute__((ext_vector_type(4)));

#define L_SEQ 2048
#define H_DIM 2048
#define KV_DIM 512
#define QKV_LD 3072
#define INTER_DIM 8192

__device__ __forceinline__ void load_lds16(const void* g, void* l) {
  __builtin_amdgcn_global_load_lds(
      (const __attribute__((address_space(1))) void*)g,
      (__attribute__((address_space(3))) void*)l, 16, 0, 0);
}

// ---------------- fused fp32 -> bf16 convert of all 7 weights -------------
// block b handles 2048 elems; segment boundaries are block-aligned.
__global__ __launch_bounds__(256)
void cvt_all(const float* __restrict__ q, const float* __restrict__ k,
             const float* __restrict__ v, const float* __restrict__ o,
             const float* __restrict__ g, const float* __restrict__ u,
             const float* __restrict__ dn, bf16* __restrict__ WB) {
  const int b = blockIdx.x;
  const float* s;
  size_t doff;
  int lb;
  if (b < 2048)       { s = q;  doff = 0;        lb = b; }
  else if (b < 2560)  { s = k;  doff = 4194304;  lb = b - 2048; }
  else if (b < 3072)  { s = v;  doff = 5242880;  lb = b - 2560; }
  else if (b < 5120)  { s = o;  doff = 6291456;  lb = b - 3072; }
  else if (b < 13312) { s = g;  doff = 10485760; lb = b - 5120; }
  else if (b < 21504) { s = u;  doff = 27262976; lb = b - 13312; }
  else                { s = dn; doff = 44040192; lb = b - 21504; }
  const size_t i = (size_t)lb * 2048 + threadIdx.x * 8;
  float4 a = *(const float4*)(s + i);
  float4 c = *(const float4*)(s + i + 4);
  bf16x8 ov;
  ov[0] = (bf16)a.x; ov[1] = (bf16)a.y; ov[2] = (bf16)a.z; ov[3] = (bf16)a.w;
  ov[4] = (bf16)c.x; ov[5] = (bf16)c.y; ov[6] = (bf16)c.z; ov[7] = (bf16)c.w;
  *(bf16x8*)(WB + doff + i) = ov;
}

// ---------------- RMSNorm: fp32 in -> bf16 out ----------------
__global__ __launch_bounds__(256)
void rmsnorm_bf16(const float* __restrict__ x, const float* __restrict__ w,
                  bf16* __restrict__ out) {
  const int row = blockIdx.x;
  const int t = threadIdx.x;
  const float* xr = x + (size_t)row * H_DIM + t * 8;
  float4 a = *(const float4*)xr;
  float4 b = *(const float4*)(xr + 4);
  float ss = a.x * a.x + a.y * a.y + a.z * a.z + a.w * a.w +
             b.x * b.x + b.y * b.y + b.z * b.z + b.w * b.w;
#pragma unroll
  for (int off = 1; off < 64; off <<= 1) ss += __shfl_xor(ss, off, 64);
  __shared__ float red[4];
  if ((t & 63) == 0) red[t >> 6] = ss;
  __syncthreads();
  ss = red[0] + red[1] + red[2] + red[3];
  const float rs = rsqrtf(ss * (1.0f / H_DIM) + 1e-6f);
  float4 w1 = *(const float4*)(w + t * 8);
  float4 w2 = *(const float4*)(w + t * 8 + 4);
  bf16x8 o;
  o[0] = (bf16)(a.x * rs * w1.x);
  o[1] = (bf16)(a.y * rs * w1.y);
  o[2] = (bf16)(a.z * rs * w1.z);
  o[3] = (bf16)(a.w * rs * w1.w);
  o[4] = (bf16)(b.x * rs * w2.x);
  o[5] = (bf16)(b.y * rs * w2.y);
  o[6] = (bf16)(b.z * rs * w2.z);
  o[7] = (bf16)(b.w * rs * w2.w);
  *(bf16x8*)(out + (size_t)row * H_DIM + t * 8) = o;
}

// -------- fused: hidden = p0+p1+res (fp32 out) ; normed = rmsnorm(hidden) --
__global__ __launch_bounds__(256)
void add_rmsnorm(const float* __restrict__ p0, const float* __restrict__ p1,
                 const float* __restrict__ res, const float* __restrict__ w,
                 float* __restrict__ hidden, bf16* __restrict__ normed) {
  const int row = blockIdx.x;
  const int t = threadIdx.x;
  const size_t base = (size_t)row * H_DIM + t * 8;
  float4 a0 = *(const float4*)(p0 + base);
  float4 a1 = *(const float4*)(p0 + base + 4);
  float4 b0 = *(const float4*)(p1 + base);
  float4 b1 = *(const float4*)(p1 + base + 4);
  float4 c0 = *(const float4*)(res + base);
  float4 c1 = *(const float4*)(res + base + 4);
  float4 h0, h1;
  h0.x = a0.x + b0.x + c0.x; h0.y = a0.y + b0.y + c0.y;
  h0.z = a0.z + b0.z + c0.z; h0.w = a0.w + b0.w + c0.w;
  h1.x = a1.x + b1.x + c1.x; h1.y = a1.y + b1.y + c1.y;
  h1.z = a1.z + b1.z + c1.z; h1.w = a1.w + b1.w + c1.w;
  *(float4*)(hidden + base) = h0;
  *(float4*)(hidden + base + 4) = h1;
  float ss = h0.x * h0.x + h0.y * h0.y + h0.z * h0.z + h0.w * h0.w +
             h1.x * h1.x + h1.y * h1.y + h1.z * h1.z + h1.w * h1.w;
#pragma unroll
  for (int off = 1; off < 64; off <<= 1) ss += __shfl_xor(ss, off, 64);
  __shared__ float red[4];
  if ((t & 63) == 0) red[t >> 6] = ss;
  __syncthreads();
  ss = red[0] + red[1] + red[2] + red[3];
  const float rs = rsqrtf(ss * (1.0f / H_DIM) + 1e-6f);
  float4 w1 = *(const float4*)(w + t * 8);
  float4 w2 = *(const float4*)(w + t * 8 + 4);
  bf16x8 o;
  o[0] = (bf16)(h0.x * rs * w1.x);
  o[1] = (bf16)(h0.y * rs * w1.y);
  o[2] = (bf16)(h0.z * rs * w1.z);
  o[3] = (bf16)(h0.w * rs * w1.w);
  o[4] = (bf16)(h1.x * rs * w2.x);
  o[5] = (bf16)(h1.y * rs * w2.y);
  o[6] = (bf16)(h1.z * rs * w2.z);
  o[7] = (bf16)(h1.w * rs * w2.w);
  *(bf16x8*)(normed + (size_t)row * H_DIM + t * 8) = o;
}

// ---------------- out = p0+p1+p2+p3 + res (float4) ----------------
__global__ __launch_bounds__(256)
void reduce_add4(const float* __restrict__ p, size_t zs,
                 const float* __restrict__ res, float* __restrict__ out) {
  const size_t i = ((size_t)blockIdx.x * 256 + threadIdx.x) * 4;
  float4 a = *(const float4*)(p + i);
  float4 b = *(const float4*)(p + zs + i);
  float4 c = *(const float4*)(p + 2 * zs + i);
  float4 d = *(const float4*)(p + 3 * zs + i);
  float4 r = *(const float4*)(res + i);
  float4 o;
  o.x = a.x + b.x + c.x + d.x + r.x;
  o.y = a.y + b.y + c.y + d.y + r.y;
  o.z = a.z + b.z + c.z + d.z + r.z;
  o.w = a.w + b.w + c.w + d.w + r.w;
  *(float4*)(out + i) = o;
}

// ---------------- GEMM: C[M,N] = A[M,K](bf16) @ B[N,K](bf16)^T -------------
enum { M_PART = 0, M_QKV = 1 };

template <int MODE>
__global__ __launch_bounds__(256, 2)
void gemm_bt(const bf16* __restrict__ A, int lda,
             const bf16* __restrict__ B, int ldb, int kpb,
             bf16* __restrict__ outb,
             float* __restrict__ outf, int ldof, size_t zstride,
             float* __restrict__ outk, float* __restrict__ outv) {
  __shared__ bf16 sA[128 * 32];
  __shared__ bf16 sB[128 * 32];
  const int t = threadIdx.x;
  const int lane = t & 63;
  const int l15 = lane & 15, l4 = lane >> 4;
  const int wm = ((t >> 6) >> 1) * 64;
  const int wn = ((t >> 6) & 1) * 64;
  const int m0 = blockIdx.y * 128;
  const int n0 = blockIdx.x * 128;
  const int kbeg = blockIdx.z * kpb;
  const int kend = kbeg + kpb;

  const f32x4 zero = {0.f, 0.f, 0.f, 0.f};
  f32x4 acc[4][4];
#pragma unroll
  for (int i = 0; i < 4; ++i)
#pragma unroll
    for (int j = 0; j < 4; ++j) acc[i][j] = zero;

  for (int k0 = kbeg; k0 < kend; k0 += 32) {
#pragma unroll
    for (int i = 0; i < 2; ++i) {
      const int flat = i * 4096 + t * 16;
      const int r = flat >> 6, cb = (flat & 63) >> 1;
      load_lds16(A + (size_t)(m0 + r) * lda + k0 + cb, (char*)sA + flat);
      load_lds16(B + (size_t)(n0 + r) * ldb + k0 + cb, (char*)sB + flat);
    }
    __syncthreads();

    bf16x8 af[4], bfr[4];
#pragma unroll
    for (int mi = 0; mi < 4; ++mi)
      af[mi] = *(const bf16x8*)(&sA[(wm + mi * 16 + l15) * 32 + l4 * 8]);
#pragma unroll
    for (int ni = 0; ni < 4; ++ni)
      bfr[ni] = *(const bf16x8*)(&sB[(wn + ni * 16 + l15) * 32 + l4 * 8]);
#pragma unroll
    for (int mi = 0; mi < 4; ++mi)
#pragma unroll
      for (int ni = 0; ni < 4; ++ni)
        acc[mi][ni] = __builtin_amdgcn_mfma_f32_16x16x32_bf16(
            af[mi], bfr[ni], acc[mi][ni], 0, 0, 0);
    __syncthreads();
  }

  // C/D layout: col = lane&15, row = (lane>>4)*4 + reg (m89/m91).
#pragma unroll
  for (int mi = 0; mi < 4; ++mi) {
#pragma unroll
    for (int ni = 0; ni < 4; ++ni) {
      const int row0 = m0 + wm + mi * 16 + l4 * 4;
      const int col = n0 + wn + ni * 16 + l15;
#pragma unroll
      for (int r = 0; r < 4; ++r) {
        const float c = acc[mi][ni][r];
        const size_t m = (size_t)(row0 + r);
        if (MODE == M_PART) {
          outf[zstride * blockIdx.z + m * ldof + col] = c;
        } else {  // M_QKV
          outb[m * QKV_LD + col] = (bf16)c;
          if (col >= 2560)      outv[m * KV_DIM + (col - 2560)] = c;
          else if (col >= 2048) outk[m * KV_DIM + (col - 2048)] = c;
        }
      }
    }
  }
}

// ---------------- Fused gate+up GLU GEMM ----------------
__global__ __launch_bounds__(256, 2)
void gemm_glu(const bf16* __restrict__ A, const bf16* __restrict__ Bg,
              const bf16* __restrict__ Bu, bf16* __restrict__ out) {
  __shared__ bf16 sA[128 * 32];
  __shared__ bf16 sG[128 * 32];
  __shared__ bf16 sU[128 * 32];
  const int t = threadIdx.x;
  const int lane = t & 63;
  const int l15 = lane & 15, l4 = lane >> 4;
  const int wm = ((t >> 6) >> 1) * 64;
  const int wn = ((t >> 6) & 1) * 64;
  const int m0 = blockIdx.y * 128;
  const int n0 = blockIdx.x * 128;

  const f32x4 zero = {0.f, 0.f, 0.f, 0.f};
  f32x4 ag[4][4], au[4][4];
#pragma unroll
  for (int i = 0; i < 4; ++i)
#pragma unroll
    for (int j = 0; j < 4; ++j) { ag[i][j] = zero; au[i][j] = zero; }

  for (int k0 = 0; k0 < H_DIM; k0 += 32) {
#pragma unroll
    for (int i = 0; i < 2; ++i) {
      const int flat = i * 4096 + t * 16;
      const int r = flat >> 6, cb = (flat & 63) >> 1;
      load_lds16(A + (size_t)(m0 + r) * H_DIM + k0 + cb, (char*)sA + flat);
      load_lds16(Bg + (size_t)(n0 + r) * H_DIM + k0 + cb, (char*)sG + flat);
      load_lds16(Bu + (size_t)(n0 + r) * H_DIM + k0 + cb, (char*)sU + flat);
    }
    __syncthreads();

    bf16x8 af[4], bg[4], bu[4];
#pragma unroll
    for (int mi = 0; mi < 4; ++mi)
      af[mi] = *(const bf16x8*)(&sA[(wm + mi * 16 + l15) * 32 + l4 * 8]);
#pragma unroll
    for (int ni = 0; ni < 4; ++ni) {
      bg[ni] = *(const bf16x8*)(&sG[(wn + ni * 16 + l15) * 32 + l4 * 8]);
      bu[ni] = *(const bf16x8*)(&sU[(wn + ni * 16 + l15) * 32 + l4 * 8]);
    }
#pragma unroll
    for (int mi = 0; mi < 4; ++mi)
#pragma unroll
      for (int ni = 0; ni < 4; ++ni) {
        ag[mi][ni] = __builtin_amdgcn_mfma_f32_16x16x32_bf16(
            af[mi], bg[ni], ag[mi][ni], 0, 0, 0);
        au[mi][ni] = __builtin_amdgcn_mfma_f32_16x16x32_bf16(
            af[mi], bu[ni], au[mi][ni], 0, 0, 0);
      }
    __syncthreads();
  }

#pragma unroll
  for (int mi = 0; mi < 4; ++mi) {
#pragma unroll
    for (int ni = 0; ni < 4; ++ni) {
      const int row0 = m0 + wm + mi * 16 + l4 * 4;
      const int col = n0 + wn + ni * 16 + l15;
#pragma unroll
      for (int r = 0; r < 4; ++r) {
        const float g = ag[mi][ni][r];
        const float u = au[mi][ni][r];
        const float s = g / (1.f + __expf(-g));
        out[(size_t)(row0 + r) * INTER_DIM + col] = (bf16)(s * u);
      }
    }
  }
}

// ---------------- Flash attention, segment-causal ----------------
// V staged TRANSPOSED in LDS (sVt[d][k], stride 72) so PV B-fragments are
// single ds_read_b128 (was 128 scalar ds_read_u16 per wave-iter).
__global__ __launch_bounds__(256, 2)
void attn_fwd(const bf16* __restrict__ qkv, const int* __restrict__ cu,
              bf16* __restrict__ out) {
  const int h = blockIdx.y;
  const int q0 = blockIdx.x * 64;
  const int kvh = h >> 2;
  const int t = threadIdx.x;
  const int lane = t & 63;
  const int w = t >> 6;
  const int l15 = lane & 15, l4 = lane >> 4;

  __shared__ bf16 sK[64 * 136];   // key-major, stride 136 elems
  __shared__ bf16 sVt[128 * 72];  // d-major (transposed), stride 72 elems
  __shared__ bf16 sP[4][16 * 64];

  const int c1 = cu[1], c2 = cu[2];
  const int seg0 = (q0 >= c2) ? c2 : ((q0 >= c1) ? c1 : 0);

  const int qrow = q0 + w * 16 + l15;
  bf16x8 qf[4];
#pragma unroll
  for (int kc = 0; kc < 4; ++kc) {
    bf16x8 v = *(const bf16x8*)(qkv + (size_t)qrow * QKV_LD + h * 128 +
                                kc * 32 + l4 * 8);
#pragma unroll
    for (int j = 0; j < 8; ++j)
      v[j] = (bf16)((float)v[j] * 0.08838834764831845f);
    qf[kc] = v;
  }

  const f32x4 zero = {0.f, 0.f, 0.f, 0.f};
  f32x4 oacc[8];
#pragma unroll
  for (int i = 0; i < 8; ++i) oacc[i] = zero;
  float mi[4] = {-1e30f, -1e30f, -1e30f, -1e30f};
  float li[4] = {0.f, 0.f, 0.f, 0.f};

  for (int k0 = seg0; k0 <= q0; k0 += 64) {
#pragma unroll
    for (int it = 0; it < 4; ++it) {
      // K: coalesced, key-major
      const int flat = it * 4096 + t * 16;
      const int r = flat >> 8, db = flat & 255;
      *(bf16x8*)((char*)sK + r * 272 + db) = *(const bf16x8*)(
          (const char*)(qkv + (size_t)(k0 + r) * QKV_LD + 2048 + kvh * 128) +
          db);
      // V: key-scattered 16B loads, transposed scalar LDS writes
      // (write lanes share d, span keys -> conflict-free)
      const int chunk = it * 256 + t;
      const int vr = chunk & 63, dc = chunk >> 6;
      bf16x8 vv = *(const bf16x8*)(qkv + (size_t)(k0 + vr) * QKV_LD + 2560 +
                                   kvh * 128 + dc * 8);
#pragma unroll
      for (int j = 0; j < 8; ++j) sVt[(dc * 8 + j) * 72 + vr] = vv[j];
    }
    __syncthreads();

    f32x4 sacc[4];
#pragma unroll
    for (int kg = 0; kg < 4; ++kg) {
      f32x4 a = zero;
#pragma unroll
      for (int kc = 0; kc < 4; ++kc) {
        bf16x8 kf = *(const bf16x8*)((const char*)sK + (kg * 16 + l15) * 272 +
                                     kc * 64 + l4 * 16);
        a = __builtin_amdgcn_mfma_f32_16x16x32_bf16(qf[kc], kf, a, 0, 0, 0);
      }
      sacc[kg] = a;
    }

    if (k0 == q0) {
#pragma unroll
      for (int kg = 0; kg < 4; ++kg) {
        const int kk = kg * 16 + l15;
#pragma unroll
        for (int r = 0; r < 4; ++r) {
          const int qq = w * 16 + l4 * 4 + r;
          if (kk > qq) sacc[kg][r] = -1e30f;
        }
      }
    }

    float mx[4], al[4], rs[4];
#pragma unroll
    for (int r = 0; r < 4; ++r)
      mx[r] = fmaxf(fmaxf(sacc[0][r], sacc[1][r]),
                    fmaxf(sacc[2][r], sacc[3][r]));
#pragma unroll
    for (int off = 1; off < 16; off <<= 1)
#pragma unroll
      for (int r = 0; r < 4; ++r)
        mx[r] = fmaxf(mx[r], __shfl_xor(mx[r], off, 64));
#pragma unroll
    for (int r = 0; r < 4; ++r) {
      const float mn = fmaxf(mi[r], mx[r]);
      al[r] = __expf(mi[r] - mn);
      mi[r] = mn;
      rs[r] = 0.f;
    }
#pragma unroll
    for (int kg = 0; kg < 4; ++kg)
#pragma unroll
      for (int r = 0; r < 4; ++r) {
        const float p = __expf(sacc[kg][r] - mi[r]);
        sacc[kg][r] = p;
        rs[r] += p;
      }
#pragma unroll
    for (int off = 1; off < 16; off <<= 1)
#pragma unroll
      for (int r = 0; r < 4; ++r) rs[r] += __shfl_xor(rs[r], off, 64);
#pragma unroll
    for (int r = 0; r < 4; ++r) li[r] = li[r] * al[r] + rs[r];
#pragma unroll
    for (int dn = 0; dn < 8; ++dn)
#pragma unroll
      for (int r = 0; r < 4; ++r) oacc[dn][r] *= al[r];

    // P: C-layout -> LDS -> A-layout. sP[w] is wave-private: no barrier
    // needed (compiler inserts lgkmcnt waits for own writes).
#pragma unroll
    for (int kg = 0; kg < 4; ++kg)
#pragma unroll
      for (int r = 0; r < 4; ++r)
        sP[w][(l4 * 4 + r) * 64 + kg * 16 + l15] = (bf16)sacc[kg][r];

    bf16x8 pf[2];
#pragma unroll
    for (int kc2 = 0; kc2 < 2; ++kc2)
      pf[kc2] = *(const bf16x8*)(&sP[w][l15 * 64 + kc2 * 32 + l4 * 8]);
#pragma unroll
    for (int dn = 0; dn < 8; ++dn)
#pragma unroll
      for (int kc2 = 0; kc2 < 2; ++kc2) {
        bf16x8 vf = *(const bf16x8*)(&sVt[(dn * 16 + l15) * 72 + kc2 * 32 +
                                          l4 * 8]);
        oacc[dn] = __builtin_amdgcn_mfma_f32_16x16x32_bf16(pf[kc2], vf,
                                                           oacc[dn], 0, 0, 0);
      }
    __syncthreads();
  }

#pragma unroll
  for (int dn = 0; dn < 8; ++dn)
#pragma unroll
    for (int r = 0; r < 4; ++r) {
      const size_t m = (size_t)(q0 + w * 16 + l4 * 4 + r);
      out[m * H_DIM + h * 128 + dn * 16 + l15] = (bf16)(oacc[dn][r] / li[r]);
    }
}

// ---------------- Host launcher ----------------
extern "C" void kernel_launch(void* const* d_in, const int* in_sizes, int n_in,
                              void* d_out, int out_size, void* d_ws,
                              size_t ws_size, hipStream_t stream) {
  (void)in_sizes; (void)n_in; (void)out_size; (void)ws_size;
  const float* hs     = (const float*)d_in[0];
  const int*   cu     = (const int*)d_in[1];
  const float* ln1    = (const float*)d_in[2];
  const float* ln2    = (const float*)d_in[3];
  const float* q_w    = (const float*)d_in[4];
  const float* k_w    = (const float*)d_in[5];
  const float* v_w    = (const float*)d_in[6];
  const float* o_w    = (const float*)d_in[7];
  const float* gate_w = (const float*)d_in[8];
  const float* up_w   = (const float*)d_in[9];
  const float* down_w = (const float*)d_in[10];

  float* out_hidden = (float*)d_out;  // fp32 hidden lives here
  float* out_k = out_hidden + (size_t)L_SEQ * H_DIM;
  float* out_v = out_k + (size_t)L_SEQ * KV_DIM;

  char* ws = (char*)d_ws;
  // bf16 weights: q@0 | k@20MiB... (elem offsets below), total 116 MiB
  bf16* WB = (bf16*)ws;
  const size_t wq_off = 0;
  const size_t wo_off = 6291456;
  const size_t wg_off = 10485760;
  const size_t wu_off = 27262976;
  const size_t wd_off = 44040192;

  bf16*  normed1 = (bf16*)(ws + ((size_t)116 << 20));   //  8 MiB
  bf16*  qkv     = (bf16*)(ws + ((size_t)124 << 20));   // 12 MiB
  bf16*  attnb   = (bf16*)(ws + ((size_t)136 << 20));   //  8 MiB
  bf16*  normed2 = (bf16*)(ws + ((size_t)144 << 20));   //  8 MiB
  bf16*  interb  = (bf16*)(ws + ((size_t)152 << 20));   // 32 MiB (ends 184)
  // O-proj partials overlay interb (free until GLU)
  float* opart   = (float*)(ws + ((size_t)152 << 20));  // 2 x 16 MiB
  // down-proj partials overlay gate+up bf16 weights (free after GLU):
  // bytes [20 MiB, 84 MiB) = 64 MiB = 4 x 16 MiB
  float* dpart   = (float*)(ws + ((size_t)20 << 20));

  dim3 blk(256);

  // 0) convert all weights to bf16 (one dispatch)
  cvt_all<<<29696, blk, 0, stream>>>(q_w, k_w, v_w, o_w, gate_w, up_w, down_w,
                                     WB);

  // 1) normed1 = rmsnorm(hidden_states)
  rmsnorm_bf16<<<L_SEQ, blk, 0, stream>>>(hs, ln1, normed1);

  // 2) QKV projection (B = stacked q|k|v, N = 3072)
  gemm_bt<M_QKV><<<dim3(24, 16, 1), blk, 0, stream>>>(
      normed1, H_DIM, WB + wq_off, H_DIM, H_DIM, qkv, nullptr, 0, 0, out_k,
      out_v);

  // 3) attention
  attn_fwd<<<dim3(32, 16), blk, 0, stream>>>(qkv, cu, attnb);

  // 4) O projection, split-K=2 -> partials
  gemm_bt<M_PART><<<dim3(16, 16, 2), blk, 0, stream>>>(
      attnb, H_DIM, WB + wo_off, H_DIM, 1024, nullptr, opart, H_DIM,
      (size_t)L_SEQ * H_DIM, nullptr, nullptr);

  // 5) hidden = opart0+opart1+hs ; normed2 = rmsnorm(hidden)   (fused)
  add_rmsnorm<<<L_SEQ, blk, 0, stream>>>(opart, opart + (size_t)L_SEQ * H_DIM,
                                         hs, ln2, out_hidden, normed2);

  // 6) inter = silu(normed2 @ gate^T) * (normed2 @ up^T)  (fused GLU)
  gemm_glu<<<dim3(64, 16), blk, 0, stream>>>(normed2, WB + wg_off, WB + wu_off,
                                             interb);

  // 7) down projection, split-K=4 -> partials
  gemm_bt<M_PART><<<dim3(16, 16, 4), blk, 0, stream>>>(
      interb, INTER_DIM, WB + wd_off, INTER_DIM, 2048, nullptr, dpart, H_DIM,
      (size_t)L_SEQ * H_DIM, nullptr, nullptr);

  // 8) out = sum(dpart[0..3]) + hidden (in place on d_out)
  reduce_add4<<<4096, blk, 0, stream>>>(dpart, (size_t)L_SEQ * H_DIM,
                                        out_hidden, out_hidden);
}

// Round 4
// 651.281 us; speedup vs baseline: 1.3408x; 1.0210x over previous
//
#include <hip/hip_runtime.h>
#include <stdint.h>

typedef __bf16 bf16;
typedef __bf16 bf16x8 __attribute__((ext_vector_type(8)));
typedef __bf16 bf16x4v __attribute__((ext_vector_type(4)));
typedef float f32x4 __attribute__((ext_vector_type(4)));

#define L_SEQ 2048
#define H_DIM 2048
#define KV_DIM 512
#define QKV_LD 3072
#define INTER_DIM 8192

__device__ __forceinline__ void load_lds16(const void* g, void* l) {
  __builtin_amdgcn_global_load_lds(
      (const __attribute__((address_space(1))) void*)g,
      (__attribute__((address_space(3))) void*)l, 16, 0, 0);
}

// ---------------- fused fp32 -> bf16 convert of all 7 weights -------------
__global__ __launch_bounds__(256)
void cvt_all(const float* __restrict__ q, const float* __restrict__ k,
             const float* __restrict__ v, const float* __restrict__ o,
             const float* __restrict__ g, const float* __restrict__ u,
             const float* __restrict__ dn, bf16* __restrict__ WB) {
  const int b = blockIdx.x;
  const float* s;
  size_t doff;
  int lb;
  if (b < 2048)       { s = q;  doff = 0;        lb = b; }
  else if (b < 2560)  { s = k;  doff = 4194304;  lb = b - 2048; }
  else if (b < 3072)  { s = v;  doff = 5242880;  lb = b - 2560; }
  else if (b < 5120)  { s = o;  doff = 6291456;  lb = b - 3072; }
  else if (b < 13312) { s = g;  doff = 10485760; lb = b - 5120; }
  else if (b < 21504) { s = u;  doff = 27262976; lb = b - 13312; }
  else                { s = dn; doff = 44040192; lb = b - 21504; }
  const size_t i = (size_t)lb * 2048 + threadIdx.x * 8;
  float4 a = *(const float4*)(s + i);
  float4 c = *(const float4*)(s + i + 4);
  bf16x8 ov;
  ov[0] = (bf16)a.x; ov[1] = (bf16)a.y; ov[2] = (bf16)a.z; ov[3] = (bf16)a.w;
  ov[4] = (bf16)c.x; ov[5] = (bf16)c.y; ov[6] = (bf16)c.z; ov[7] = (bf16)c.w;
  *(bf16x8*)(WB + doff + i) = ov;
}

// ---------------- RMSNorm: fp32 in -> bf16 out ----------------
__global__ __launch_bounds__(256)
void rmsnorm_bf16(const float* __restrict__ x, const float* __restrict__ w,
                  bf16* __restrict__ out) {
  const int row = blockIdx.x;
  const int t = threadIdx.x;
  const float* xr = x + (size_t)row * H_DIM + t * 8;
  float4 a = *(const float4*)xr;
  float4 b = *(const float4*)(xr + 4);
  float ss = a.x * a.x + a.y * a.y + a.z * a.z + a.w * a.w +
             b.x * b.x + b.y * b.y + b.z * b.z + b.w * b.w;
#pragma unroll
  for (int off = 1; off < 64; off <<= 1) ss += __shfl_xor(ss, off, 64);
  __shared__ float red[4];
  if ((t & 63) == 0) red[t >> 6] = ss;
  __syncthreads();
  ss = red[0] + red[1] + red[2] + red[3];
  const float rs = rsqrtf(ss * (1.0f / H_DIM) + 1e-6f);
  float4 w1 = *(const float4*)(w + t * 8);
  float4 w2 = *(const float4*)(w + t * 8 + 4);
  bf16x8 o;
  o[0] = (bf16)(a.x * rs * w1.x);
  o[1] = (bf16)(a.y * rs * w1.y);
  o[2] = (bf16)(a.z * rs * w1.z);
  o[3] = (bf16)(a.w * rs * w1.w);
  o[4] = (bf16)(b.x * rs * w2.x);
  o[5] = (bf16)(b.y * rs * w2.y);
  o[6] = (bf16)(b.z * rs * w2.z);
  o[7] = (bf16)(b.w * rs * w2.w);
  *(bf16x8*)(out + (size_t)row * H_DIM + t * 8) = o;
}

// -------- fused: hidden = p0+p1+res ; normed = rmsnorm(hidden) --------
__global__ __launch_bounds__(256)
void add_rmsnorm(const float* __restrict__ p0, const float* __restrict__ p1,
                 const float* __restrict__ res, const float* __restrict__ w,
                 float* __restrict__ hidden, bf16* __restrict__ normed) {
  const int row = blockIdx.x;
  const int t = threadIdx.x;
  const size_t base = (size_t)row * H_DIM + t * 8;
  float4 a0 = *(const float4*)(p0 + base);
  float4 a1 = *(const float4*)(p0 + base + 4);
  float4 b0 = *(const float4*)(p1 + base);
  float4 b1 = *(const float4*)(p1 + base + 4);
  float4 c0 = *(const float4*)(res + base);
  float4 c1 = *(const float4*)(res + base + 4);
  float4 h0, h1;
  h0.x = a0.x + b0.x + c0.x; h0.y = a0.y + b0.y + c0.y;
  h0.z = a0.z + b0.z + c0.z; h0.w = a0.w + b0.w + c0.w;
  h1.x = a1.x + b1.x + c1.x; h1.y = a1.y + b1.y + c1.y;
  h1.z = a1.z + b1.z + c1.z; h1.w = a1.w + b1.w + c1.w;
  *(float4*)(hidden + base) = h0;
  *(float4*)(hidden + base + 4) = h1;
  float ss = h0.x * h0.x + h0.y * h0.y + h0.z * h0.z + h0.w * h0.w +
             h1.x * h1.x + h1.y * h1.y + h1.z * h1.z + h1.w * h1.w;
#pragma unroll
  for (int off = 1; off < 64; off <<= 1) ss += __shfl_xor(ss, off, 64);
  __shared__ float red[4];
  if ((t & 63) == 0) red[t >> 6] = ss;
  __syncthreads();
  ss = red[0] + red[1] + red[2] + red[3];
  const float rs = rsqrtf(ss * (1.0f / H_DIM) + 1e-6f);
  float4 w1 = *(const float4*)(w + t * 8);
  float4 w2 = *(const float4*)(w + t * 8 + 4);
  bf16x8 o;
  o[0] = (bf16)(h0.x * rs * w1.x);
  o[1] = (bf16)(h0.y * rs * w1.y);
  o[2] = (bf16)(h0.z * rs * w1.z);
  o[3] = (bf16)(h0.w * rs * w1.w);
  o[4] = (bf16)(h1.x * rs * w2.x);
  o[5] = (bf16)(h1.y * rs * w2.y);
  o[6] = (bf16)(h1.z * rs * w2.z);
  o[7] = (bf16)(h1.w * rs * w2.w);
  *(bf16x8*)(normed + (size_t)row * H_DIM + t * 8) = o;
}

// ---------------- out = p0+p1+p2+p3 + res (float4) ----------------
__global__ __launch_bounds__(256)
void reduce_add4(const float* __restrict__ p, size_t zs,
                 const float* __restrict__ res, float* __restrict__ out) {
  const size_t i = ((size_t)blockIdx.x * 256 + threadIdx.x) * 4;
  float4 a = *(const float4*)(p + i);
  float4 b = *(const float4*)(p + zs + i);
  float4 c = *(const float4*)(p + 2 * zs + i);
  float4 d = *(const float4*)(p + 3 * zs + i);
  float4 r = *(const float4*)(res + i);
  float4 o;
  o.x = a.x + b.x + c.x + d.x + r.x;
  o.y = a.y + b.y + c.y + d.y + r.y;
  o.z = a.z + b.z + c.z + d.z + r.z;
  o.w = a.w + b.w + c.w + d.w + r.w;
  *(float4*)(out + i) = o;
}

// ------- qkv combine: sum 2 fp32 partials -> bf16 qkv + fp32 K/V out ------
__global__ __launch_bounds__(256)
void qkv_combine(const float* __restrict__ p, size_t zs,
                 bf16* __restrict__ qkv, float* __restrict__ outk,
                 float* __restrict__ outv) {
  const size_t i = ((size_t)blockIdx.x * 256 + threadIdx.x) * 4;
  float4 a = *(const float4*)(p + i);
  float4 b = *(const float4*)(p + zs + i);
  float4 s;
  s.x = a.x + b.x; s.y = a.y + b.y; s.z = a.z + b.z; s.w = a.w + b.w;
  bf16x4v o;
  o[0] = (bf16)s.x; o[1] = (bf16)s.y; o[2] = (bf16)s.z; o[3] = (bf16)s.w;
  *(bf16x4v*)(qkv + i) = o;
  const int col = (int)(i % QKV_LD);
  const size_t row = i / QKV_LD;
  if (col >= 2560)      *(float4*)(outv + row * KV_DIM + (col - 2560)) = s;
  else if (col >= 2048) *(float4*)(outk + row * KV_DIM + (col - 2048)) = s;
}

// ---------------- GEMM: C[M,N] = A[M,K](bf16) @ B[N,K](bf16)^T -------------
// 128x128 tile, BK=64 (two 32-wide k-chunks stacked in LDS: [kc][128][32],
// row stride 64 B -> same bank behavior as m97; pad-free for global_load_lds).
// Writes fp32 partials indexed by blockIdx.z (split-K).
__global__ __launch_bounds__(256, 3)
void gemm_bt(const bf16* __restrict__ A, int lda,
             const bf16* __restrict__ B, int ldb, int kpb,
             float* __restrict__ outf, int ldof, size_t zstride) {
  __shared__ bf16 sA[2 * 128 * 32];
  __shared__ bf16 sB[2 * 128 * 32];
  const int t = threadIdx.x;
  const int lane = t & 63;
  const int l15 = lane & 15, l4 = lane >> 4;
  const int wm = ((t >> 6) >> 1) * 64;
  const int wn = ((t >> 6) & 1) * 64;
  const int m0 = blockIdx.y * 128;
  const int n0 = blockIdx.x * 128;
  const int kbeg = blockIdx.z * kpb;
  const int kend = kbeg + kpb;

  const f32x4 zero = {0.f, 0.f, 0.f, 0.f};
  f32x4 acc[4][4];
#pragma unroll
  for (int i = 0; i < 4; ++i)
#pragma unroll
    for (int j = 0; j < 4; ++j) acc[i][j] = zero;

  for (int k0 = kbeg; k0 < kend; k0 += 64) {
#pragma unroll
    for (int i = 0; i < 4; ++i) {
      const int flat = i * 4096 + t * 16;           // byte offset in tile
      const int kc = flat >> 13;                    // 8192 B per k-chunk
      const int wb = flat & 8191;
      const int r = wb >> 6, ce = (wb & 63) >> 1;   // row, col-elem in chunk
      const int gc = k0 + kc * 32 + ce;
      load_lds16(A + (size_t)(m0 + r) * lda + gc, (char*)sA + flat);
      load_lds16(B + (size_t)(n0 + r) * ldb + gc, (char*)sB + flat);
    }
    __syncthreads();

#pragma unroll
    for (int kc = 0; kc < 2; ++kc) {
      bf16x8 af[4], bfr[4];
#pragma unroll
      for (int mi = 0; mi < 4; ++mi)
        af[mi] = *(const bf16x8*)(&sA[kc * 4096 + (wm + mi * 16 + l15) * 32 +
                                      l4 * 8]);
#pragma unroll
      for (int ni = 0; ni < 4; ++ni)
        bfr[ni] = *(const bf16x8*)(&sB[kc * 4096 + (wn + ni * 16 + l15) * 32 +
                                       l4 * 8]);
#pragma unroll
      for (int mi = 0; mi < 4; ++mi)
#pragma unroll
        for (int ni = 0; ni < 4; ++ni)
          acc[mi][ni] = __builtin_amdgcn_mfma_f32_16x16x32_bf16(
              af[mi], bfr[ni], acc[mi][ni], 0, 0, 0);
    }
    __syncthreads();
  }

  // C/D layout: col = lane&15, row = (lane>>4)*4 + reg (m89/m91).
#pragma unroll
  for (int mi = 0; mi < 4; ++mi) {
#pragma unroll
    for (int ni = 0; ni < 4; ++ni) {
      const int row0 = m0 + wm + mi * 16 + l4 * 4;
      const int col = n0 + wn + ni * 16 + l15;
#pragma unroll
      for (int r = 0; r < 4; ++r)
        outf[zstride * blockIdx.z + (size_t)(row0 + r) * ldof + col] =
            acc[mi][ni][r];
    }
  }
}

// ---------------- Fused gate+up GLU GEMM (BK=64) ----------------
__global__ __launch_bounds__(256, 2)
void gemm_glu(const bf16* __restrict__ A, const bf16* __restrict__ Bg,
              const bf16* __restrict__ Bu, bf16* __restrict__ out) {
  __shared__ bf16 sA[2 * 128 * 32];
  __shared__ bf16 sG[2 * 128 * 32];
  __shared__ bf16 sU[2 * 128 * 32];
  const int t = threadIdx.x;
  const int lane = t & 63;
  const int l15 = lane & 15, l4 = lane >> 4;
  const int wm = ((t >> 6) >> 1) * 64;
  const int wn = ((t >> 6) & 1) * 64;
  const int m0 = blockIdx.y * 128;
  const int n0 = blockIdx.x * 128;

  const f32x4 zero = {0.f, 0.f, 0.f, 0.f};
  f32x4 ag[4][4], au[4][4];
#pragma unroll
  for (int i = 0; i < 4; ++i)
#pragma unroll
    for (int j = 0; j < 4; ++j) { ag[i][j] = zero; au[i][j] = zero; }

  for (int k0 = 0; k0 < H_DIM; k0 += 64) {
#pragma unroll
    for (int i = 0; i < 4; ++i) {
      const int flat = i * 4096 + t * 16;
      const int kc = flat >> 13;
      const int wb = flat & 8191;
      const int r = wb >> 6, ce = (wb & 63) >> 1;
      const int gc = k0 + kc * 32 + ce;
      load_lds16(A + (size_t)(m0 + r) * H_DIM + gc, (char*)sA + flat);
      load_lds16(Bg + (size_t)(n0 + r) * H_DIM + gc, (char*)sG + flat);
      load_lds16(Bu + (size_t)(n0 + r) * H_DIM + gc, (char*)sU + flat);
    }
    __syncthreads();

#pragma unroll
    for (int kc = 0; kc < 2; ++kc) {
      bf16x8 af[4], bg[4], bu[4];
#pragma unroll
      for (int mi = 0; mi < 4; ++mi)
        af[mi] = *(const bf16x8*)(&sA[kc * 4096 + (wm + mi * 16 + l15) * 32 +
                                      l4 * 8]);
#pragma unroll
      for (int ni = 0; ni < 4; ++ni) {
        bg[ni] = *(const bf16x8*)(&sG[kc * 4096 + (wn + ni * 16 + l15) * 32 +
                                      l4 * 8]);
        bu[ni] = *(const bf16x8*)(&sU[kc * 4096 + (wn + ni * 16 + l15) * 32 +
                                      l4 * 8]);
      }
#pragma unroll
      for (int mi = 0; mi < 4; ++mi)
#pragma unroll
        for (int ni = 0; ni < 4; ++ni) {
          ag[mi][ni] = __builtin_amdgcn_mfma_f32_16x16x32_bf16(
              af[mi], bg[ni], ag[mi][ni], 0, 0, 0);
          au[mi][ni] = __builtin_amdgcn_mfma_f32_16x16x32_bf16(
              af[mi], bu[ni], au[mi][ni], 0, 0, 0);
        }
    }
    __syncthreads();
  }

#pragma unroll
  for (int mi = 0; mi < 4; ++mi) {
#pragma unroll
    for (int ni = 0; ni < 4; ++ni) {
      const int row0 = m0 + wm + mi * 16 + l4 * 4;
      const int col = n0 + wn + ni * 16 + l15;
#pragma unroll
      for (int r = 0; r < 4; ++r) {
        const float g = ag[mi][ni][r];
        const float u = au[mi][ni][r];
        const float s = g / (1.f + __expf(-g));
        out[(size_t)(row0 + r) * INTER_DIM + col] = (bf16)(s * u);
      }
    }
  }
}

// ---------------- Flash attention, segment-causal ----------------
__global__ __launch_bounds__(256, 2)
void attn_fwd(const bf16* __restrict__ qkv, const int* __restrict__ cu,
              bf16* __restrict__ out) {
  const int h = blockIdx.y;
  const int q0 = blockIdx.x * 64;
  const int kvh = h >> 2;
  const int t = threadIdx.x;
  const int lane = t & 63;
  const int w = t >> 6;
  const int l15 = lane & 15, l4 = lane >> 4;

  __shared__ bf16 sK[64 * 136];   // key-major, stride 136 elems
  __shared__ bf16 sVt[128 * 72];  // d-major (transposed), stride 72 elems
  __shared__ bf16 sP[4][16 * 64];

  const int c1 = cu[1], c2 = cu[2];
  const int seg0 = (q0 >= c2) ? c2 : ((q0 >= c1) ? c1 : 0);

  const int qrow = q0 + w * 16 + l15;
  bf16x8 qf[4];
#pragma unroll
  for (int kc = 0; kc < 4; ++kc) {
    bf16x8 v = *(const bf16x8*)(qkv + (size_t)qrow * QKV_LD + h * 128 +
                                kc * 32 + l4 * 8);
#pragma unroll
    for (int j = 0; j < 8; ++j)
      v[j] = (bf16)((float)v[j] * 0.08838834764831845f);
    qf[kc] = v;
  }

  const f32x4 zero = {0.f, 0.f, 0.f, 0.f};
  f32x4 oacc[8];
#pragma unroll
  for (int i = 0; i < 8; ++i) oacc[i] = zero;
  float mi[4] = {-1e30f, -1e30f, -1e30f, -1e30f};
  float li[4] = {0.f, 0.f, 0.f, 0.f};

  for (int k0 = seg0; k0 <= q0; k0 += 64) {
#pragma unroll
    for (int it = 0; it < 4; ++it) {
      const int flat = it * 4096 + t * 16;
      const int r = flat >> 8, db = flat & 255;
      *(bf16x8*)((char*)sK + r * 272 + db) = *(const bf16x8*)(
          (const char*)(qkv + (size_t)(k0 + r) * QKV_LD + 2048 + kvh * 128) +
          db);
      const int chunk = it * 256 + t;
      const int vr = chunk & 63, dc = chunk >> 6;
      bf16x8 vv = *(const bf16x8*)(qkv + (size_t)(k0 + vr) * QKV_LD + 2560 +
                                   kvh * 128 + dc * 8);
#pragma unroll
      for (int j = 0; j < 8; ++j) sVt[(dc * 8 + j) * 72 + vr] = vv[j];
    }
    __syncthreads();

    f32x4 sacc[4];
#pragma unroll
    for (int kg = 0; kg < 4; ++kg) {
      f32x4 a = zero;
#pragma unroll
      for (int kc = 0; kc < 4; ++kc) {
        bf16x8 kf = *(const bf16x8*)((const char*)sK + (kg * 16 + l15) * 272 +
                                     kc * 64 + l4 * 16);
        a = __builtin_amdgcn_mfma_f32_16x16x32_bf16(qf[kc], kf, a, 0, 0, 0);
      }
      sacc[kg] = a;
    }

    if (k0 == q0) {
#pragma unroll
      for (int kg = 0; kg < 4; ++kg) {
        const int kk = kg * 16 + l15;
#pragma unroll
        for (int r = 0; r < 4; ++r) {
          const int qq = w * 16 + l4 * 4 + r;
          if (kk > qq) sacc[kg][r] = -1e30f;
        }
      }
    }

    float mx[4], al[4], rs[4];
#pragma unroll
    for (int r = 0; r < 4; ++r)
      mx[r] = fmaxf(fmaxf(sacc[0][r], sacc[1][r]),
                    fmaxf(sacc[2][r], sacc[3][r]));
#pragma unroll
    for (int off = 1; off < 16; off <<= 1)
#pragma unroll
      for (int r = 0; r < 4; ++r)
        mx[r] = fmaxf(mx[r], __shfl_xor(mx[r], off, 64));
#pragma unroll
    for (int r = 0; r < 4; ++r) {
      const float mn = fmaxf(mi[r], mx[r]);
      al[r] = __expf(mi[r] - mn);
      mi[r] = mn;
      rs[r] = 0.f;
    }
#pragma unroll
    for (int kg = 0; kg < 4; ++kg)
#pragma unroll
      for (int r = 0; r < 4; ++r) {
        const float p = __expf(sacc[kg][r] - mi[r]);
        sacc[kg][r] = p;
        rs[r] += p;
      }
#pragma unroll
    for (int off = 1; off < 16; off <<= 1)
#pragma unroll
      for (int r = 0; r < 4; ++r) rs[r] += __shfl_xor(rs[r], off, 64);
#pragma unroll
    for (int r = 0; r < 4; ++r) li[r] = li[r] * al[r] + rs[r];
#pragma unroll
    for (int dn = 0; dn < 8; ++dn)
#pragma unroll
      for (int r = 0; r < 4; ++r) oacc[dn][r] *= al[r];

#pragma unroll
    for (int kg = 0; kg < 4; ++kg)
#pragma unroll
      for (int r = 0; r < 4; ++r)
        sP[w][(l4 * 4 + r) * 64 + kg * 16 + l15] = (bf16)sacc[kg][r];

    bf16x8 pf[2];
#pragma unroll
    for (int kc2 = 0; kc2 < 2; ++kc2)
      pf[kc2] = *(const bf16x8*)(&sP[w][l15 * 64 + kc2 * 32 + l4 * 8]);
#pragma unroll
    for (int dn = 0; dn < 8; ++dn)
#pragma unroll
      for (int kc2 = 0; kc2 < 2; ++kc2) {
        bf16x8 vf = *(const bf16x8*)(&sVt[(dn * 16 + l15) * 72 + kc2 * 32 +
                                          l4 * 8]);
        oacc[dn] = __builtin_amdgcn_mfma_f32_16x16x32_bf16(pf[kc2], vf,
                                                           oacc[dn], 0, 0, 0);
      }
    __syncthreads();
  }

#pragma unroll
  for (int dn = 0; dn < 8; ++dn)
#pragma unroll
    for (int r = 0; r < 4; ++r) {
      const size_t m = (size_t)(q0 + w * 16 + l4 * 4 + r);
      out[m * H_DIM + h * 128 + dn * 16 + l15] = (bf16)(oacc[dn][r] / li[r]);
    }
}

// ---------------- Host launcher ----------------
extern "C" void kernel_launch(void* const* d_in, const int* in_sizes, int n_in,
                              void* d_out, int out_size, void* d_ws,
                              size_t ws_size, hipStream_t stream) {
  (void)in_sizes; (void)n_in; (void)out_size; (void)ws_size;
  const float* hs     = (const float*)d_in[0];
  const int*   cu     = (const int*)d_in[1];
  const float* ln1    = (const float*)d_in[2];
  const float* ln2    = (const float*)d_in[3];
  const float* q_w    = (const float*)d_in[4];
  const float* k_w    = (const float*)d_in[5];
  const float* v_w    = (const float*)d_in[6];
  const float* o_w    = (const float*)d_in[7];
  const float* gate_w = (const float*)d_in[8];
  const float* up_w   = (const float*)d_in[9];
  const float* down_w = (const float*)d_in[10];

  float* out_hidden = (float*)d_out;  // fp32 hidden lives here
  float* out_k = out_hidden + (size_t)L_SEQ * H_DIM;
  float* out_v = out_k + (size_t)L_SEQ * KV_DIM;

  char* ws = (char*)d_ws;
  // bf16 weights (elem offsets): q@0|k@8MiB|v@10|o@12|gate@20|up@52|down@84
  bf16* WB = (bf16*)ws;
  const size_t wq_off = 0;
  const size_t wo_off = 6291456;
  const size_t wg_off = 10485760;
  const size_t wu_off = 27262976;
  const size_t wd_off = 44040192;

  bf16*  normed1 = (bf16*)(ws + ((size_t)116 << 20));   //  8 MiB
  bf16*  qkv     = (bf16*)(ws + ((size_t)124 << 20));   // 12 MiB
  bf16*  attnb   = (bf16*)(ws + ((size_t)136 << 20));   //  8 MiB
  bf16*  normed2 = (bf16*)(ws + ((size_t)144 << 20));   //  8 MiB
  bf16*  interb  = (bf16*)(ws + ((size_t)152 << 20));   // 32 MiB (ends 184)
  // qkv fp32 partials (2 x 24 MiB) overlay [136,184) — dead until attn
  float* qpart   = (float*)(ws + ((size_t)136 << 20));
  // O-proj partials (2 x 16 MiB) overlay interb [152,184) — dead until GLU
  float* opart   = (float*)(ws + ((size_t)152 << 20));
  // down-proj partials (4 x 16 MiB) overlay q..up weights [0,64) — dead
  // after GLU (down weight lives at [84,116))
  float* dpart   = (float*)(ws);

  dim3 blk(256);

  // 0) convert all weights to bf16 (one dispatch)
  cvt_all<<<29696, blk, 0, stream>>>(q_w, k_w, v_w, o_w, gate_w, up_w, down_w,
                                     WB);

  // 1) normed1 = rmsnorm(hidden_states)
  rmsnorm_bf16<<<L_SEQ, blk, 0, stream>>>(hs, ln1, normed1);

  // 2) QKV projection, split-K=2 -> fp32 partials; then combine
  gemm_bt<<<dim3(24, 16, 2), blk, 0, stream>>>(
      normed1, H_DIM, WB + wq_off, H_DIM, 1024, qpart, QKV_LD,
      (size_t)L_SEQ * QKV_LD);
  qkv_combine<<<6144, blk, 0, stream>>>(qpart, (size_t)L_SEQ * QKV_LD, qkv,
                                        out_k, out_v);

  // 3) attention
  attn_fwd<<<dim3(32, 16), blk, 0, stream>>>(qkv, cu, attnb);

  // 4) O projection, split-K=2 -> partials
  gemm_bt<<<dim3(16, 16, 2), blk, 0, stream>>>(
      attnb, H_DIM, WB + wo_off, H_DIM, 1024, opart, H_DIM,
      (size_t)L_SEQ * H_DIM);

  // 5) hidden = opart0+opart1+hs ; normed2 = rmsnorm(hidden)   (fused)
  add_rmsnorm<<<L_SEQ, blk, 0, stream>>>(opart, opart + (size_t)L_SEQ * H_DIM,
                                         hs, ln2, out_hidden, normed2);

  // 6) inter = silu(normed2 @ gate^T) * (normed2 @ up^T)  (fused GLU)
  gemm_glu<<<dim3(64, 16), blk, 0, stream>>>(normed2, WB + wg_off, WB + wu_off,
                                             interb);

  // 7) down projection, split-K=4 -> partials
  gemm_bt<<<dim3(16, 16, 4), blk, 0, stream>>>(
      interb, INTER_DIM, WB + wd_off, INTER_DIM, 2048, dpart, H_DIM,
      (size_t)L_SEQ * H_DIM);

  // 8) out = sum(dpart[0..3]) + hidden (in place on d_out)
  reduce_add4<<<4096, blk, 0, stream>>>(dpart, (size_t)L_SEQ * H_DIM,
                                        out_hidden, out_hidden);
}